// Round 2
// baseline (4130.373 us; speedup 1.0000x reference)
//
#include <hip/hip_runtime.h>
#include <hip/hip_bf16.h>

typedef float  v4f __attribute__((ext_vector_type(4)));
typedef short  v8s __attribute__((ext_vector_type(8)));
typedef int    v4i __attribute__((ext_vector_type(4)));

#define DEV static __device__ __forceinline__

DEV float bf2f(unsigned short u) {
    union { unsigned int i; float f; } x; x.i = ((unsigned int)u) << 16; return x.f;
}
DEV unsigned short f2bf(float f) {
    union { float f; unsigned int i; } x; x.f = f;
    unsigned int r = x.i + 0x7fff + ((x.i >> 16) & 1);
    return (unsigned short)(r >> 16);
}
DEV float sigm(float x) { return 1.f / (1.f + __expf(-x)); }

DEV v4i pack8(const float* f) {
    v4i o;
#pragma unroll
    for (int q = 0; q < 4; ++q)
        ((unsigned int*)&o)[q] = (unsigned int)f2bf(f[2 * q]) |
                                 ((unsigned int)f2bf(f[2 * q + 1]) << 16);
    return o;
}
DEV float lo16(unsigned int x) { union { unsigned int i; float f; } u; u.i = x << 16; return u.f; }
DEV float hi16(unsigned int x) { union { unsigned int i; float f; } u; u.i = x & 0xffff0000u; return u.f; }

// Software grid barrier: monotonic counter, device-scope atomics.
// Safe because grid (256 blocks) <= guaranteed-resident capacity (>=1 block/CU
// by LDS: 47KB -> 3 blocks/CU; 256 CUs). seq*256 is the arrival target.
DEV void gbar(int* cnt, int target) {
    __syncthreads();
    if (threadIdx.x == 0) {
        __threadfence();   // release: write back this XCD's dirty lines
        __hip_atomic_fetch_add(cnt, 1, __ATOMIC_RELEASE, __HIP_MEMORY_SCOPE_AGENT);
        while (__hip_atomic_load(cnt, __ATOMIC_ACQUIRE, __HIP_MEMORY_SCOPE_AGENT) < target)
            __builtin_amdgcn_s_sleep(2);
        __threadfence();   // acquire: invalidate stale lines before reading peers' data
    }
    __syncthreads();
}

// ---------------------------------------------------------------------------
// uber_init: 8 elements per thread, 16B loads + 16B stores.
// ---------------------------------------------------------------------------
__global__ __launch_bounds__(256) void uber_init(
    const float* __restrict__ Wih, const float* __restrict__ Whh,
    const float* __restrict__ bih, const float* __restrict__ bhh,
    const float* __restrict__ WoutF, const float* __restrict__ WeattF,
    const float* __restrict__ WdattF, const float* __restrict__ Wh0F,
    const float* __restrict__ Wc0F, const float* __restrict__ enc,
    const int* __restrict__ caps, const float* __restrict__ embed,
    unsigned short* __restrict__ Wz, unsigned short* __restrict__ Woutb,
    unsigned short* __restrict__ Weattb, unsigned short* __restrict__ Wdattb,
    unsigned short* __restrict__ Wh0b, unsigned short* __restrict__ Wc0b,
    unsigned short* __restrict__ encb, unsigned short* __restrict__ embb,
    unsigned short* __restrict__ meanb, float* __restrict__ bz)
{
    const int i = (blockIdx.x * 256 + threadIdx.x) * 8;
    float f[8];
    if (i < 11534336) {                       // Wz = [W_ih | W_hh] rows of 2816
        int n = i / 2816, k = i - n * 2816;
        const float* src = (k < 1792) ? &Wih[n * 1792 + k] : &Whh[n * 1024 + (k - 1792)];
        *(v4f*)&f[0] = *(const v4f*)src; *(v4f*)&f[4] = *(const v4f*)(src + 4);
        *(v4i*)&Wz[i] = pack8(f);
    } else if (i < 21774336) {                // W_out
        int j = i - 11534336;
        *(v4f*)&f[0] = *(const v4f*)&WoutF[j]; *(v4f*)&f[4] = *(const v4f*)&WoutF[j + 4];
        *(v4i*)&Woutb[j] = pack8(f);
    } else if (i < 22429696) {                // W_eatt
        int j = i - 21774336;
        *(v4f*)&f[0] = *(const v4f*)&WeattF[j]; *(v4f*)&f[4] = *(const v4f*)&WeattF[j + 4];
        *(v4i*)&Weattb[j] = pack8(f);
    } else if (i < 22953984) {                // W_datt
        int j = i - 22429696;
        *(v4f*)&f[0] = *(const v4f*)&WdattF[j]; *(v4f*)&f[4] = *(const v4f*)&WdattF[j + 4];
        *(v4i*)&Wdattb[j] = pack8(f);
    } else if (i < 24264704) {                // W_h0
        int j = i - 22953984;
        *(v4f*)&f[0] = *(const v4f*)&Wh0F[j]; *(v4f*)&f[4] = *(const v4f*)&Wh0F[j + 4];
        *(v4i*)&Wh0b[j] = pack8(f);
    } else if (i < 25575424) {                // W_c0
        int j = i - 24264704;
        *(v4f*)&f[0] = *(const v4f*)&Wc0F[j]; *(v4f*)&f[4] = *(const v4f*)&Wc0F[j + 4];
        *(v4i*)&Wc0b[j] = pack8(f);
    } else if (i < 29589504) {                // encoder_out
        int j = i - 25575424;
        *(v4f*)&f[0] = *(const v4f*)&enc[j]; *(v4f*)&f[4] = *(const v4f*)&enc[j + 4];
        *(v4i*)&encb[j] = pack8(f);
    } else if (i < 30375936) {                // emb gather (t < 24 only)
        int j = i - 29589504;
        int b = j / 12288, r = j - b * 12288, t = r / 512, e = r - t * 512;
        const float* src = &embed[caps[b * 25 + t] * 512 + e];
        *(v4f*)&f[0] = *(const v4f*)src; *(v4f*)&f[4] = *(const v4f*)(src + 4);
        *(v4i*)&embb[j] = pack8(f);
    } else if (i < 30457856) {                // mean over P=49
        int j = i - 30375936;
        int b = j / 1280, c = j - b * 1280;
#pragma unroll
        for (int q = 0; q < 8; ++q) f[q] = 0.f;
        for (int p = 0; p < 49; ++p) {
            const float* src = &enc[(b * 49 + p) * 1280 + c];
            v4f a = *(const v4f*)src, bq = *(const v4f*)(src + 4);
#pragma unroll
            for (int q = 0; q < 4; ++q) { f[q] += a[q]; f[q + 4] += bq[q]; }
        }
#pragma unroll
        for (int q = 0; q < 8; ++q) f[q] *= (1.f / 49.f);
        *(v4i*)&meanb[j] = pack8(f);
    } else if (i < 30461952) {                // bz = b_ih + b_hh
        int j = i - 30457856;
#pragma unroll
        for (int q = 0; q < 8; ++q) f[q] = bih[j + q] + bhh[j + q];
        *(v4f*)&bz[j] = *(v4f*)&f[0]; *(v4f*)&bz[j + 4] = *(v4f*)&f[4];
    }
}

// ---------------------------------------------------------------------------
// gemm64_bn16: C[64,N] = A[64,K](bf16) @ B[N,K](bf16)^T + bias. BN=16/block.
// Register-double-buffered staging. (used for h0/c0 init only)
// ---------------------------------------------------------------------------
template <int OUT_BF16>
__global__ __launch_bounds__(256) void gemm64_bn16(
    const unsigned short* __restrict__ Ag, int lda,
    const unsigned short* __restrict__ Bg, int K,
    const float* __restrict__ bias, void* __restrict__ Cg, int ldc)
{
    __shared__ unsigned short lA[64 * 264];
    __shared__ unsigned short lB[16 * 264];
    const int tid = threadIdx.x, lane = tid & 63, w = tid >> 6;
    const int nb = blockIdx.x * 16;
    const int rA = tid >> 5, cA = (tid & 31) * 8;
    v4f acc = {0.f, 0.f, 0.f, 0.f};
    v4i ra[8], rb[2];
#pragma unroll
    for (int i = 0; i < 8; ++i)
        ra[i] = *(const v4i*)&Ag[(rA + i * 8) * lda + cA];
#pragma unroll
    for (int i = 0; i < 2; ++i)
        rb[i] = *(const v4i*)&Bg[(nb + rA + i * 8) * K + cA];
    for (int kt = 0; kt < K; kt += 256) {
#pragma unroll
        for (int i = 0; i < 8; ++i) *(v4i*)&lA[(rA + i * 8) * 264 + cA] = ra[i];
#pragma unroll
        for (int i = 0; i < 2; ++i) *(v4i*)&lB[(rA + i * 8) * 264 + cA] = rb[i];
        __syncthreads();
        if (kt + 256 < K) {
#pragma unroll
            for (int i = 0; i < 8; ++i)
                ra[i] = *(const v4i*)&Ag[(rA + i * 8) * lda + kt + 256 + cA];
#pragma unroll
            for (int i = 0; i < 2; ++i)
                rb[i] = *(const v4i*)&Bg[(nb + rA + i * 8) * K + kt + 256 + cA];
        }
#pragma unroll
        for (int ks = 0; ks < 8; ++ks) {
            v8s a = *(const v8s*)&lA[(w * 16 + (lane & 15)) * 264 + ks * 32 + (lane >> 4) * 8];
            v8s b = *(const v8s*)&lB[(lane & 15) * 264 + ks * 32 + (lane >> 4) * 8];
            acc = __builtin_amdgcn_mfma_f32_16x16x32_bf16(a, b, acc, 0, 0, 0);
        }
        __syncthreads();
    }
    const int n = nb + (lane & 15);
    const float bs = bias[n];
#pragma unroll
    for (int r = 0; r < 4; ++r) {
        int m = w * 16 + (lane >> 4) * 4 + r;
        float v = acc[r] + bs;
        if (OUT_BF16) ((unsigned short*)Cg)[m * ldc + n] = f2bf(v);
        else          ((float*)Cg)[m * ldc + n] = v;
    }
}

// ---------------------------------------------------------------------------
// gemm_att1: att1[3136,512](bf16) = enc_b[3136,1280] @ W_eatt[512,1280]^T + b
// Tile 64x64, BK=128, reg-dbuf. grid = (8, 49)
// ---------------------------------------------------------------------------
__global__ __launch_bounds__(256) void gemm_att1_k(
    const unsigned short* __restrict__ Aenc, const unsigned short* __restrict__ Bw,
    const float* __restrict__ bias, unsigned short* __restrict__ Cout)
{
    __shared__ unsigned short lA[64 * 136];
    __shared__ unsigned short lB[64 * 136];
    const int tid = threadIdx.x, lane = tid & 63, w = tid >> 6;
    const int mb = blockIdx.y * 64, nb = blockIdx.x * 64;
    const int rT = tid >> 4, cT = (tid & 15) * 8;
    v4f acc[4];
#pragma unroll
    for (int f = 0; f < 4; ++f) acc[f] = (v4f){0.f, 0.f, 0.f, 0.f};
    v4i ra[4], rb[4];
#pragma unroll
    for (int i = 0; i < 4; ++i) {
        ra[i] = *(const v4i*)&Aenc[(mb + rT + i * 16) * 1280 + cT];
        rb[i] = *(const v4i*)&Bw[(nb + rT + i * 16) * 1280 + cT];
    }
    for (int kt = 0; kt < 1280; kt += 128) {
#pragma unroll
        for (int i = 0; i < 4; ++i) {
            *(v4i*)&lA[(rT + i * 16) * 136 + cT] = ra[i];
            *(v4i*)&lB[(rT + i * 16) * 136 + cT] = rb[i];
        }
        __syncthreads();
        if (kt + 128 < 1280) {
#pragma unroll
            for (int i = 0; i < 4; ++i) {
                ra[i] = *(const v4i*)&Aenc[(mb + rT + i * 16) * 1280 + kt + 128 + cT];
                rb[i] = *(const v4i*)&Bw[(nb + rT + i * 16) * 1280 + kt + 128 + cT];
            }
        }
#pragma unroll
        for (int ks = 0; ks < 4; ++ks) {
            v8s a = *(const v8s*)&lA[(w * 16 + (lane & 15)) * 136 + ks * 32 + (lane >> 4) * 8];
#pragma unroll
            for (int f = 0; f < 4; ++f) {
                v8s b = *(const v8s*)&lB[(f * 16 + (lane & 15)) * 136 + ks * 32 + (lane >> 4) * 8];
                acc[f] = __builtin_amdgcn_mfma_f32_16x16x32_bf16(a, b, acc[f], 0, 0, 0);
            }
        }
        __syncthreads();
    }
#pragma unroll
    for (int f = 0; f < 4; ++f) {
        int n = nb + f * 16 + (lane & 15);
        float bs = bias[n];
#pragma unroll
        for (int r = 0; r < 4; ++r) {
            int m = mb + w * 16 + (lane >> 4) * 4 + r;
            Cout[m * 512 + n] = f2bf(acc[f][r] + bs);
        }
    }
}

// ---------------------------------------------------------------------------
// loop_k: the full 24-step decoder loop in one persistent kernel, regular
// launch + software grid barrier (no cooperative machinery). grid = 256
// blocks x 256 threads, LDS 47KB -> all blocks guaranteed co-resident.
//   phase 1 (blocks 0..31):  att2[64,512] = h @ Wdatt^T + b   (MFMA tile)
//   phase 2 (blocks 0..63):  scores/softmax/ctx per b; builds z = [emb|ctx|h]
//   phase 3 (all 256):       gates = z @ Wz^T + bz; LSTM epilogue -> hnew,Hall
// h double-buffered in hnewb (avoids WAR between h-read and h-write).
// ---------------------------------------------------------------------------
struct SmemGemm {
    unsigned short lA[64 * 264];
    unsigned short lB[16 * 264];
    float gbuf[64 * 20];
};
struct SmemAttn {
    float a2[512];
    float wf[512];
    float es[64];
    float alpha[64];
};
union LoopSmem { SmemGemm g; SmemAttn a; };

__global__ __launch_bounds__(256, 1) void loop_k(
    float* __restrict__ att2, unsigned short* __restrict__ zb,
    const unsigned short* __restrict__ Wdattb, const float* __restrict__ bdatt,
    const unsigned short* __restrict__ att1b, const float* __restrict__ Wfatt,
    const float* __restrict__ bfatt, const unsigned short* __restrict__ encb,
    const unsigned short* __restrict__ embb, const unsigned short* __restrict__ Wzb,
    const float* __restrict__ bz, float* __restrict__ cst,
    unsigned short* __restrict__ Hallb, unsigned short* __restrict__ hnewb,
    int* __restrict__ barcnt)
{
    __shared__ LoopSmem sm;
    const int tid = threadIdx.x, lane = tid & 63, w = tid >> 6;
    const int bid = blockIdx.x;
    int btarget = 0;

    for (int t = 0; t < 24; ++t) {
        // ---------------- phase 1: att2 = h @ Wdatt^T + bdatt (blocks 0..31)
        if (bid < 32) {
            const int nb = bid * 16;
            const int rA = tid >> 5, cA = (tid & 31) * 8;
            v4f acc = {0.f, 0.f, 0.f, 0.f};
            v4i ra[8], rb[2];
#pragma unroll
            for (int i = 0; i < 8; ++i)
                ra[i] = *(const v4i*)&hnewb[(rA + i * 8) * 1024 + cA];
#pragma unroll
            for (int i = 0; i < 2; ++i)
                rb[i] = *(const v4i*)&Wdattb[(nb + rA + i * 8) * 1024 + cA];
            for (int kt = 0; kt < 1024; kt += 256) {
#pragma unroll
                for (int i = 0; i < 8; ++i) *(v4i*)&sm.g.lA[(rA + i * 8) * 264 + cA] = ra[i];
#pragma unroll
                for (int i = 0; i < 2; ++i) *(v4i*)&sm.g.lB[(rA + i * 8) * 264 + cA] = rb[i];
                __syncthreads();
                if (kt + 256 < 1024) {
#pragma unroll
                    for (int i = 0; i < 8; ++i)
                        ra[i] = *(const v4i*)&hnewb[(rA + i * 8) * 1024 + kt + 256 + cA];
#pragma unroll
                    for (int i = 0; i < 2; ++i)
                        rb[i] = *(const v4i*)&Wdattb[(nb + rA + i * 8) * 1024 + kt + 256 + cA];
                }
#pragma unroll
                for (int ks = 0; ks < 8; ++ks) {
                    v8s a = *(const v8s*)&sm.g.lA[(w * 16 + (lane & 15)) * 264 + ks * 32 + (lane >> 4) * 8];
                    v8s b = *(const v8s*)&sm.g.lB[(lane & 15) * 264 + ks * 32 + (lane >> 4) * 8];
                    acc = __builtin_amdgcn_mfma_f32_16x16x32_bf16(a, b, acc, 0, 0, 0);
                }
                __syncthreads();
            }
            const int n = nb + (lane & 15);
            const float bs = bdatt[n];
#pragma unroll
            for (int r = 0; r < 4; ++r) {
                int m = w * 16 + (lane >> 4) * 4 + r;
                att2[m * 512 + n] = acc[r] + bs;
            }
        }
        btarget += 256; gbar(barcnt, btarget);

        // ---------------- phase 2: attention + z assembly (blocks 0..63)
        if (bid < 64) {
            const int b = bid;
            float* a2 = sm.a.a2; float* wf = sm.a.wf;
            float* es = sm.a.es; float* alpha = sm.a.alpha;
            a2[tid]       = att2[b * 512 + tid];
            a2[tid + 256] = att2[b * 512 + tid + 256];
            wf[tid]       = Wfatt[tid];
            wf[tid + 256] = Wfatt[tid + 256];
            __syncthreads();
            for (int p = w; p < 49; p += 4) {
                v4i u = *(const v4i*)&att1b[(b * 49 + p) * 512 + lane * 8];
                v4f c0 = *(const v4f*)&a2[lane * 8], c1 = *(const v4f*)&a2[lane * 8 + 4];
                v4f w0 = *(const v4f*)&wf[lane * 8], w1 = *(const v4f*)&wf[lane * 8 + 4];
                float s = 0.f;
#pragma unroll
                for (int q = 0; q < 4; ++q) {
                    unsigned int x = ((unsigned int*)&u)[q];
                    float vlo = lo16(x), vhi = hi16(x);
                    float clo = (q < 2) ? c0[q * 2] : c1[q * 2 - 4];
                    float chi = (q < 2) ? c0[q * 2 + 1] : c1[q * 2 - 3];
                    float wlo = (q < 2) ? w0[q * 2] : w1[q * 2 - 4];
                    float whi = (q < 2) ? w0[q * 2 + 1] : w1[q * 2 - 3];
                    s += fmaxf(vlo + clo, 0.f) * wlo;
                    s += fmaxf(vhi + chi, 0.f) * whi;
                }
#pragma unroll
                for (int off = 32; off > 0; off >>= 1) s += __shfl_xor(s, off);
                if (lane == 0) es[p] = s + bfatt[0];
            }
            __syncthreads();
            if (w == 0) {
                float v = (lane < 49) ? es[lane] : -1e30f;
                float m = v;
#pragma unroll
                for (int off = 32; off > 0; off >>= 1) m = fmaxf(m, __shfl_xor(m, off));
                float e = (lane < 49) ? __expf(v - m) : 0.f;
                float s = e;
#pragma unroll
                for (int off = 32; off > 0; off >>= 1) s += __shfl_xor(s, off);
                if (lane < 49) alpha[lane] = e / s;
            }
            __syncthreads();
            if (tid < 160) {
                const int jb = tid * 8;
                float acc[8];
#pragma unroll
                for (int q = 0; q < 8; ++q) acc[q] = 0.f;
                for (int p = 0; p < 49; ++p) {
                    v4i u = *(const v4i*)&encb[(b * 49 + p) * 1280 + jb];
                    float al = alpha[p];
#pragma unroll
                    for (int q = 0; q < 4; ++q) {
                        unsigned int x = ((unsigned int*)&u)[q];
                        acc[2 * q]     += al * lo16(x);
                        acc[2 * q + 1] += al * hi16(x);
                    }
                }
                *(v4i*)&zb[b * 2816 + 512 + jb] = pack8(acc);
            }
            if (tid < 64)
                *(v4i*)&zb[b * 2816 + tid * 8] = *(const v4i*)&embb[(b * 24 + t) * 512 + tid * 8];
            if (tid < 128)
                *(v4i*)&zb[b * 2816 + 1792 + tid * 8] = *(const v4i*)&hnewb[b * 1024 + tid * 8];
        }
        btarget += 256; gbar(barcnt, btarget);

        // ---------------- phase 3: gates + LSTM epilogue (all 256 blocks)
        {
            const int hb = bid * 4;
            const int rT = tid >> 5, cT = (tid & 31) * 8;
            const int gate = rT & 3, hco = rT >> 2;
            const int growB  = (gate * 1024 + hb + hco) * 2816;
            const int growB2 = (((rT + 8) & 3) * 1024 + hb + ((rT + 8) >> 2)) * 2816;
            v4f acc = {0.f, 0.f, 0.f, 0.f};
            v4i ra[8], rb[2];
#pragma unroll
            for (int i = 0; i < 8; ++i)
                ra[i] = *(const v4i*)&zb[(rT + i * 8) * 2816 + cT];
            rb[0] = *(const v4i*)&Wzb[growB + cT];
            rb[1] = *(const v4i*)&Wzb[growB2 + cT];
            for (int kt = 0; kt < 2816; kt += 256) {
#pragma unroll
                for (int i = 0; i < 8; ++i) *(v4i*)&sm.g.lA[(rT + i * 8) * 264 + cT] = ra[i];
                *(v4i*)&sm.g.lB[rT * 264 + cT] = rb[0];
                *(v4i*)&sm.g.lB[(rT + 8) * 264 + cT] = rb[1];
                __syncthreads();
                if (kt + 256 < 2816) {
#pragma unroll
                    for (int i = 0; i < 8; ++i)
                        ra[i] = *(const v4i*)&zb[(rT + i * 8) * 2816 + kt + 256 + cT];
                    rb[0] = *(const v4i*)&Wzb[growB + kt + 256 + cT];
                    rb[1] = *(const v4i*)&Wzb[growB2 + kt + 256 + cT];
                }
#pragma unroll
                for (int ks = 0; ks < 8; ++ks) {
                    v8s a = *(const v8s*)&sm.g.lA[(w * 16 + (lane & 15)) * 264 + ks * 32 + (lane >> 4) * 8];
                    v8s b = *(const v8s*)&sm.g.lB[(lane & 15) * 264 + ks * 32 + (lane >> 4) * 8];
                    acc = __builtin_amdgcn_mfma_f32_16x16x32_bf16(a, b, acc, 0, 0, 0);
                }
                __syncthreads();
            }
#pragma unroll
            for (int r = 0; r < 4; ++r) {
                int m = w * 16 + (lane >> 4) * 4 + r;   // = b
                int n = lane & 15;                      // = hco*4 + gate
                sm.g.gbuf[m * 20 + n] = acc[r];
            }
            __syncthreads();
            const int b = tid >> 2, hc2 = tid & 3, hidx = hb + hc2;
            float gi = sm.g.gbuf[b * 20 + hc2 * 4 + 0] + bz[hidx];
            float gf = sm.g.gbuf[b * 20 + hc2 * 4 + 1] + bz[1024 + hidx];
            float gg = sm.g.gbuf[b * 20 + hc2 * 4 + 2] + bz[2048 + hidx];
            float go = sm.g.gbuf[b * 20 + hc2 * 4 + 3] + bz[3072 + hidx];
            float cn = sigm(gf) * cst[b * 1024 + hidx] + sigm(gi) * tanhf(gg);
            float hn = sigm(go) * tanhf(cn);
            cst[b * 1024 + hidx] = cn;
            unsigned short h16 = f2bf(hn);
            hnewb[b * 1024 + hidx] = h16;
            Hallb[(size_t)t * 65536 + b * 1024 + hidx] = h16;
        }
        if (t < 23) { btarget += 256; gbar(barcnt, btarget); }
        // final step: kernel completion orders Hallb before preds_k
    }
}

// ---------------------------------------------------------------------------
// preds: out = Hall[1536,1024] @ W_out[10000,1024]^T + b_out
// Tile 128x128, BK=64, reg-dbuf. grid = 960 with XCD-aware mapping:
// all 12 m-blocks of one Wout n-strip land on the same XCD so the strip is
// HBM-fetched once and L2-served 11 times (round-0 FETCH was 131MB vs 26MB
// ideal from cross-XCD strip replication).
// ---------------------------------------------------------------------------
__global__ __launch_bounds__(256) void preds_k(
    const unsigned short* __restrict__ Hall, const unsigned short* __restrict__ Wout,
    const float* __restrict__ bout, float* __restrict__ out)
{
    const int bidl = blockIdx.x;
    const int xcd = bidl & 7, loc = bidl >> 3;
    const int nbi = xcd * 10 + loc / 12;
    const int mbi = loc - (loc / 12) * 12;
    if (nbi >= 79) return;
    __shared__ unsigned short lA[128 * 72];
    __shared__ unsigned short lB[128 * 72];
    const int tid = threadIdx.x, lane = tid & 63, w = tid >> 6;
    const int mb = mbi * 128, nb = nbi * 128;
    const int rT = tid >> 3, cT = (tid & 7) * 8;
    v4f acc[2][8];
#pragma unroll
    for (int i = 0; i < 2; ++i)
#pragma unroll
        for (int f = 0; f < 8; ++f) acc[i][f] = (v4f){0.f, 0.f, 0.f, 0.f};
    v4i ra[4], rb[4];
#pragma unroll
    for (int i = 0; i < 4; ++i) {
        ra[i] = *(const v4i*)&Hall[(mb + rT + i * 32) * 1024 + cT];
        int n2 = nb + rT + i * 32; if (n2 > 9999) n2 = 9999;
        rb[i] = *(const v4i*)&Wout[n2 * 1024 + cT];
    }
    for (int kt = 0; kt < 1024; kt += 64) {
#pragma unroll
        for (int i = 0; i < 4; ++i) {
            *(v4i*)&lA[(rT + i * 32) * 72 + cT] = ra[i];
            *(v4i*)&lB[(rT + i * 32) * 72 + cT] = rb[i];
        }
        __syncthreads();
        if (kt + 64 < 1024) {
#pragma unroll
            for (int i = 0; i < 4; ++i) {
                ra[i] = *(const v4i*)&Hall[(mb + rT + i * 32) * 1024 + kt + 64 + cT];
                int n2 = nb + rT + i * 32; if (n2 > 9999) n2 = 9999;
                rb[i] = *(const v4i*)&Wout[n2 * 1024 + kt + 64 + cT];
            }
        }
#pragma unroll
        for (int ks = 0; ks < 2; ++ks) {
            int ko = ks * 32 + (lane >> 4) * 8;
            v8s a0 = *(const v8s*)&lA[(w * 32 + (lane & 15)) * 72 + ko];
            v8s a1 = *(const v8s*)&lA[(w * 32 + 16 + (lane & 15)) * 72 + ko];
#pragma unroll
            for (int f = 0; f < 8; ++f) {
                v8s b = *(const v8s*)&lB[(f * 16 + (lane & 15)) * 72 + ko];
                acc[0][f] = __builtin_amdgcn_mfma_f32_16x16x32_bf16(a0, b, acc[0][f], 0, 0, 0);
                acc[1][f] = __builtin_amdgcn_mfma_f32_16x16x32_bf16(a1, b, acc[1][f], 0, 0, 0);
            }
        }
        __syncthreads();
    }
#pragma unroll
    for (int f = 0; f < 8; ++f) {
        int n = nb + f * 16 + (lane & 15);
        if (n < 10000) {
            float bs = bout[n];
#pragma unroll
            for (int i = 0; i < 2; ++i)
#pragma unroll
                for (int r = 0; r < 4; ++r) {
                    int m = mb + w * 32 + i * 16 + (lane >> 4) * 4 + r;
                    int tt = m >> 6, bb = m & 63;
                    out[(bb * 24 + tt) * 10000 + n] = acc[i][f][r] + bs;
                }
        }
    }
}

// ---------------------------------------------------------------------------
extern "C" void kernel_launch(void* const* d_in, const int* in_sizes, int n_in,
                              void* d_out, int out_size, void* d_ws, size_t ws_size,
                              hipStream_t stream)
{
    const float* enc   = (const float*)d_in[0];
    const int*   caps  = (const int*)d_in[1];
    const float* embed = (const float*)d_in[2];
    const float* Weatt = (const float*)d_in[3];
    const float* beatt = (const float*)d_in[4];
    const float* Wdatt = (const float*)d_in[5];
    const float* bdatt = (const float*)d_in[6];
    const float* Wfatt = (const float*)d_in[7];
    const float* bfatt = (const float*)d_in[8];
    const float* Wih   = (const float*)d_in[9];
    const float* bih   = (const float*)d_in[10];
    const float* Whh   = (const float*)d_in[11];
    const float* bhh   = (const float*)d_in[12];
    const float* Wh0   = (const float*)d_in[13];
    const float* bh0   = (const float*)d_in[14];
    const float* Wc0   = (const float*)d_in[15];
    const float* bc0   = (const float*)d_in[16];
    const float* WoutF = (const float*)d_in[17];
    const float* bout  = (const float*)d_in[18];
    float* out = (float*)d_out;

    char* ws = (char*)d_ws;
    size_t off = 0;
    auto carve = [&](size_t bytes) -> void* {
        void* p = ws + off; off += (bytes + 255) & ~(size_t)255; return p;
    };
    unsigned short* Wzb    = (unsigned short*)carve(11534336ull * 2);
    unsigned short* Woutb  = (unsigned short*)carve(10240000ull * 2);
    unsigned short* Weattb = (unsigned short*)carve(655360ull * 2);
    unsigned short* Wdattb = (unsigned short*)carve(524288ull * 2);
    unsigned short* Wh0b   = (unsigned short*)carve(1310720ull * 2);
    unsigned short* Wc0b   = (unsigned short*)carve(1310720ull * 2);
    unsigned short* encb   = (unsigned short*)carve(4014080ull * 2);
    unsigned short* embb   = (unsigned short*)carve(786432ull * 2);
    unsigned short* meanb  = (unsigned short*)carve(81920ull * 2);
    unsigned short* att1b  = (unsigned short*)carve(1605632ull * 2);
    unsigned short* Hallb  = (unsigned short*)carve(1572864ull * 2);
    unsigned short* zb     = (unsigned short*)carve(180224ull * 2);
    unsigned short* hnewb  = (unsigned short*)carve(65536ull * 2);
    float* bz   = (float*)carve(4096ull * 4);
    float* att2 = (float*)carve(32768ull * 4);
    float* cst  = (float*)carve(65536ull * 4);
    int*   barcnt = (int*)carve(256);

    // barrier counter must be 0 at loop_k entry every iteration
    hipMemsetAsync(barcnt, 0, 256, stream);

    uber_init<<<14874, 256, 0, stream>>>(Wih, Whh, bih, bhh, WoutF, Weatt, Wdatt,
        Wh0, Wc0, enc, caps, embed, Wzb, Woutb, Weattb, Wdattb, Wh0b, Wc0b,
        encb, embb, meanb, bz);

    // h0 -> hnewb (bf16, ldc=1024); c0 -> cst (f32)
    gemm64_bn16<1><<<64, 256, 0, stream>>>(meanb, 1280, Wh0b, 1280, bh0, hnewb, 1024);
    gemm64_bn16<0><<<64, 256, 0, stream>>>(meanb, 1280, Wc0b, 1280, bc0, cst, 1024);

    gemm_att1_k<<<dim3(8, 49), 256, 0, stream>>>(encb, Weattb, beatt, att1b);

    // whole 24-step decoder loop, one persistent kernel + software barrier
    loop_k<<<256, 256, 0, stream>>>(att2, zb, Wdattb, bdatt, att1b, Wfatt,
        bfatt, encb, embb, Wzb, bz, cst, Hallb, hnewb, barcnt);

    preds_k<<<960, 256, 0, stream>>>(Hallb, Woutb, bout, out);
}

// Round 3
// 2547.082 us; speedup vs baseline: 1.6216x; 1.6216x over previous
//
#include <hip/hip_runtime.h>
#include <hip/hip_bf16.h>

typedef float  v4f __attribute__((ext_vector_type(4)));
typedef short  v8s __attribute__((ext_vector_type(8)));
typedef int    v4i __attribute__((ext_vector_type(4)));

#define DEV static __device__ __forceinline__

DEV float bf2f(unsigned short u) {
    union { unsigned int i; float f; } x; x.i = ((unsigned int)u) << 16; return x.f;
}
DEV unsigned short f2bf(float f) {
    union { float f; unsigned int i; } x; x.f = f;
    unsigned int r = x.i + 0x7fff + ((x.i >> 16) & 1);
    return (unsigned short)(r >> 16);
}
DEV float sigm(float x) { return 1.f / (1.f + __expf(-x)); }

DEV v4i pack8(const float* f) {
    v4i o;
#pragma unroll
    for (int q = 0; q < 4; ++q)
        ((unsigned int*)&o)[q] = (unsigned int)f2bf(f[2 * q]) |
                                 ((unsigned int)f2bf(f[2 * q + 1]) << 16);
    return o;
}
DEV float lo16(unsigned int x) { union { unsigned int i; float f; } u; u.i = x << 16; return u.f; }
DEV float hi16(unsigned int x) { union { unsigned int i; float f; } u; u.i = x & 0xffff0000u; return u.f; }

// Software grid barrier. Arrival: release fetch_add (one L2 writeback of this
// block's dirty lines). Spin: RELAXED agent load (coherent-scoped, NO
// invalidate) + s_sleep; periodic fetch_add(0) hedge guarantees progress even
// if relaxed loads were cache-served. Exit: ONE acquire load (one buffer_inv).
// Round-2 lesson: spinning on an ACQUIRE load invalidates the XCD L2 every
// poll iteration -> 99% idle, 10x slowdown.
DEV void gbar(int* cnt, int target) {
    __syncthreads();
    if (threadIdx.x == 0) {
        __hip_atomic_fetch_add(cnt, 1, __ATOMIC_RELEASE, __HIP_MEMORY_SCOPE_AGENT);
        for (int it = 0; ; ++it) {
            if (__hip_atomic_load(cnt, __ATOMIC_RELAXED, __HIP_MEMORY_SCOPE_AGENT) >= target)
                break;
            if ((it & 63) == 63 &&
                __hip_atomic_fetch_add(cnt, 0, __ATOMIC_RELAXED, __HIP_MEMORY_SCOPE_AGENT) >= target)
                break;
            __builtin_amdgcn_s_sleep(16);
        }
        (void)__hip_atomic_load(cnt, __ATOMIC_ACQUIRE, __HIP_MEMORY_SCOPE_AGENT);
    }
    __syncthreads();
}

// ---------------------------------------------------------------------------
// uber_init: 8 elements per thread, 16B loads + 16B stores.
// ---------------------------------------------------------------------------
__global__ __launch_bounds__(256) void uber_init(
    const float* __restrict__ Wih, const float* __restrict__ Whh,
    const float* __restrict__ bih, const float* __restrict__ bhh,
    const float* __restrict__ WoutF, const float* __restrict__ WeattF,
    const float* __restrict__ WdattF, const float* __restrict__ Wh0F,
    const float* __restrict__ Wc0F, const float* __restrict__ enc,
    const int* __restrict__ caps, const float* __restrict__ embed,
    unsigned short* __restrict__ Wz, unsigned short* __restrict__ Woutb,
    unsigned short* __restrict__ Weattb, unsigned short* __restrict__ Wdattb,
    unsigned short* __restrict__ Wh0b, unsigned short* __restrict__ Wc0b,
    unsigned short* __restrict__ encb, unsigned short* __restrict__ embb,
    unsigned short* __restrict__ meanb, float* __restrict__ bz)
{
    const int i = (blockIdx.x * 256 + threadIdx.x) * 8;
    float f[8];
    if (i < 11534336) {                       // Wz = [W_ih | W_hh] rows of 2816
        int n = i / 2816, k = i - n * 2816;
        const float* src = (k < 1792) ? &Wih[n * 1792 + k] : &Whh[n * 1024 + (k - 1792)];
        *(v4f*)&f[0] = *(const v4f*)src; *(v4f*)&f[4] = *(const v4f*)(src + 4);
        *(v4i*)&Wz[i] = pack8(f);
    } else if (i < 21774336) {                // W_out
        int j = i - 11534336;
        *(v4f*)&f[0] = *(const v4f*)&WoutF[j]; *(v4f*)&f[4] = *(const v4f*)&WoutF[j + 4];
        *(v4i*)&Woutb[j] = pack8(f);
    } else if (i < 22429696) {                // W_eatt
        int j = i - 21774336;
        *(v4f*)&f[0] = *(const v4f*)&WeattF[j]; *(v4f*)&f[4] = *(const v4f*)&WeattF[j + 4];
        *(v4i*)&Weattb[j] = pack8(f);
    } else if (i < 22953984) {                // W_datt
        int j = i - 22429696;
        *(v4f*)&f[0] = *(const v4f*)&WdattF[j]; *(v4f*)&f[4] = *(const v4f*)&WdattF[j + 4];
        *(v4i*)&Wdattb[j] = pack8(f);
    } else if (i < 24264704) {                // W_h0
        int j = i - 22953984;
        *(v4f*)&f[0] = *(const v4f*)&Wh0F[j]; *(v4f*)&f[4] = *(const v4f*)&Wh0F[j + 4];
        *(v4i*)&Wh0b[j] = pack8(f);
    } else if (i < 25575424) {                // W_c0
        int j = i - 24264704;
        *(v4f*)&f[0] = *(const v4f*)&Wc0F[j]; *(v4f*)&f[4] = *(const v4f*)&Wc0F[j + 4];
        *(v4i*)&Wc0b[j] = pack8(f);
    } else if (i < 29589504) {                // encoder_out
        int j = i - 25575424;
        *(v4f*)&f[0] = *(const v4f*)&enc[j]; *(v4f*)&f[4] = *(const v4f*)&enc[j + 4];
        *(v4i*)&encb[j] = pack8(f);
    } else if (i < 30375936) {                // emb gather (t < 24 only)
        int j = i - 29589504;
        int b = j / 12288, r = j - b * 12288, t = r / 512, e = r - t * 512;
        const float* src = &embed[caps[b * 25 + t] * 512 + e];
        *(v4f*)&f[0] = *(const v4f*)src; *(v4f*)&f[4] = *(const v4f*)(src + 4);
        *(v4i*)&embb[j] = pack8(f);
    } else if (i < 30457856) {                // mean over P=49
        int j = i - 30375936;
        int b = j / 1280, c = j - b * 1280;
#pragma unroll
        for (int q = 0; q < 8; ++q) f[q] = 0.f;
        for (int p = 0; p < 49; ++p) {
            const float* src = &enc[(b * 49 + p) * 1280 + c];
            v4f a = *(const v4f*)src, bq = *(const v4f*)(src + 4);
#pragma unroll
            for (int q = 0; q < 4; ++q) { f[q] += a[q]; f[q + 4] += bq[q]; }
        }
#pragma unroll
        for (int q = 0; q < 8; ++q) f[q] *= (1.f / 49.f);
        *(v4i*)&meanb[j] = pack8(f);
    } else if (i < 30461952) {                // bz = b_ih + b_hh
        int j = i - 30457856;
#pragma unroll
        for (int q = 0; q < 8; ++q) f[q] = bih[j + q] + bhh[j + q];
        *(v4f*)&bz[j] = *(v4f*)&f[0]; *(v4f*)&bz[j + 4] = *(v4f*)&f[4];
    }
}

// ---------------------------------------------------------------------------
// gemm64_bn16: C[64,N] = A[64,K](bf16) @ B[N,K](bf16)^T + bias. BN=16/block.
// (used for h0/c0 init only)
// ---------------------------------------------------------------------------
template <int OUT_BF16>
__global__ __launch_bounds__(256) void gemm64_bn16(
    const unsigned short* __restrict__ Ag, int lda,
    const unsigned short* __restrict__ Bg, int K,
    const float* __restrict__ bias, void* __restrict__ Cg, int ldc)
{
    __shared__ unsigned short lA[64 * 264];
    __shared__ unsigned short lB[16 * 264];
    const int tid = threadIdx.x, lane = tid & 63, w = tid >> 6;
    const int nb = blockIdx.x * 16;
    const int rA = tid >> 5, cA = (tid & 31) * 8;
    v4f acc = {0.f, 0.f, 0.f, 0.f};
    v4i ra[8], rb[2];
#pragma unroll
    for (int i = 0; i < 8; ++i)
        ra[i] = *(const v4i*)&Ag[(rA + i * 8) * lda + cA];
#pragma unroll
    for (int i = 0; i < 2; ++i)
        rb[i] = *(const v4i*)&Bg[(nb + rA + i * 8) * K + cA];
    for (int kt = 0; kt < K; kt += 256) {
#pragma unroll
        for (int i = 0; i < 8; ++i) *(v4i*)&lA[(rA + i * 8) * 264 + cA] = ra[i];
#pragma unroll
        for (int i = 0; i < 2; ++i) *(v4i*)&lB[(rA + i * 8) * 264 + cA] = rb[i];
        __syncthreads();
        if (kt + 256 < K) {
#pragma unroll
            for (int i = 0; i < 8; ++i)
                ra[i] = *(const v4i*)&Ag[(rA + i * 8) * lda + kt + 256 + cA];
#pragma unroll
            for (int i = 0; i < 2; ++i)
                rb[i] = *(const v4i*)&Bg[(nb + rA + i * 8) * K + kt + 256 + cA];
        }
#pragma unroll
        for (int ks = 0; ks < 8; ++ks) {
            v8s a = *(const v8s*)&lA[(w * 16 + (lane & 15)) * 264 + ks * 32 + (lane >> 4) * 8];
            v8s b = *(const v8s*)&lB[(lane & 15) * 264 + ks * 32 + (lane >> 4) * 8];
            acc = __builtin_amdgcn_mfma_f32_16x16x32_bf16(a, b, acc, 0, 0, 0);
        }
        __syncthreads();
    }
    const int n = nb + (lane & 15);
    const float bs = bias[n];
#pragma unroll
    for (int r = 0; r < 4; ++r) {
        int m = w * 16 + (lane >> 4) * 4 + r;
        float v = acc[r] + bs;
        if (OUT_BF16) ((unsigned short*)Cg)[m * ldc + n] = f2bf(v);
        else          ((float*)Cg)[m * ldc + n] = v;
    }
}

// ---------------------------------------------------------------------------
// gemm_att1: att1[3136,512](bf16) = enc_b[3136,1280] @ W_eatt[512,1280]^T + b
// ---------------------------------------------------------------------------
__global__ __launch_bounds__(256) void gemm_att1_k(
    const unsigned short* __restrict__ Aenc, const unsigned short* __restrict__ Bw,
    const float* __restrict__ bias, unsigned short* __restrict__ Cout)
{
    __shared__ unsigned short lA[64 * 136];
    __shared__ unsigned short lB[64 * 136];
    const int tid = threadIdx.x, lane = tid & 63, w = tid >> 6;
    const int mb = blockIdx.y * 64, nb = blockIdx.x * 64;
    const int rT = tid >> 4, cT = (tid & 15) * 8;
    v4f acc[4];
#pragma unroll
    for (int f = 0; f < 4; ++f) acc[f] = (v4f){0.f, 0.f, 0.f, 0.f};
    v4i ra[4], rb[4];
#pragma unroll
    for (int i = 0; i < 4; ++i) {
        ra[i] = *(const v4i*)&Aenc[(mb + rT + i * 16) * 1280 + cT];
        rb[i] = *(const v4i*)&Bw[(nb + rT + i * 16) * 1280 + cT];
    }
    for (int kt = 0; kt < 1280; kt += 128) {
#pragma unroll
        for (int i = 0; i < 4; ++i) {
            *(v4i*)&lA[(rT + i * 16) * 136 + cT] = ra[i];
            *(v4i*)&lB[(rT + i * 16) * 136 + cT] = rb[i];
        }
        __syncthreads();
        if (kt + 128 < 1280) {
#pragma unroll
            for (int i = 0; i < 4; ++i) {
                ra[i] = *(const v4i*)&Aenc[(mb + rT + i * 16) * 1280 + kt + 128 + cT];
                rb[i] = *(const v4i*)&Bw[(nb + rT + i * 16) * 1280 + kt + 128 + cT];
            }
        }
#pragma unroll
        for (int ks = 0; ks < 4; ++ks) {
            v8s a = *(const v8s*)&lA[(w * 16 + (lane & 15)) * 136 + ks * 32 + (lane >> 4) * 8];
#pragma unroll
            for (int f = 0; f < 4; ++f) {
                v8s b = *(const v8s*)&lB[(f * 16 + (lane & 15)) * 136 + ks * 32 + (lane >> 4) * 8];
                acc[f] = __builtin_amdgcn_mfma_f32_16x16x32_bf16(a, b, acc[f], 0, 0, 0);
            }
        }
        __syncthreads();
    }
#pragma unroll
    for (int f = 0; f < 4; ++f) {
        int n = nb + f * 16 + (lane & 15);
        float bs = bias[n];
#pragma unroll
        for (int r = 0; r < 4; ++r) {
            int m = mb + w * 16 + (lane >> 4) * 4 + r;
            Cout[m * 512 + n] = f2bf(acc[f][r] + bs);
        }
    }
}

// ---------------------------------------------------------------------------
// loop_k: 24-step decoder loop, persistent kernel, 2 software barriers/step.
//   phaseA (blocks 0..63, block b): att2row = h[b]@Wdatt^T + bdatt as in-block
//     GEMV (att2 stays in LDS -- no global round-trip, no extra barrier);
//     then scores/softmax/ctx; writes z row b = [emb | ctx | h].
//   phaseB (all 256 blocks): gates = z @ Wz^T + bz, LSTM epilogue -> hnew/Hall.
// ---------------------------------------------------------------------------
struct SmemGemm {
    unsigned short lA[64 * 264];
    unsigned short lB[16 * 264];
    float gbuf[64 * 20];
};
struct SmemAttn {
    float a2[512];
    float wf[512];
    float hf[1024];
    float es[64];
    float alpha[64];
};
union LoopSmem { SmemGemm g; SmemAttn a; };

__global__ __launch_bounds__(256, 1) void loop_k(
    unsigned short* __restrict__ zb,
    const unsigned short* __restrict__ Wdattb, const float* __restrict__ bdatt,
    const unsigned short* __restrict__ att1b, const float* __restrict__ Wfatt,
    const float* __restrict__ bfatt, const unsigned short* __restrict__ encb,
    const unsigned short* __restrict__ embb, const unsigned short* __restrict__ Wzb,
    const float* __restrict__ bz, float* __restrict__ cst,
    unsigned short* __restrict__ Hallb, unsigned short* __restrict__ hnewb,
    int* __restrict__ barcnt)
{
    __shared__ LoopSmem sm;
    const int tid = threadIdx.x, lane = tid & 63, w = tid >> 6;
    const int bid = blockIdx.x;
    int btarget = 0;

    for (int t = 0; t < 24; ++t) {
        // ============ phaseA: GEMV att2 + attention + z assembly (blocks 0..63)
        if (bid < 64) {
            const int b = bid;
            float* a2 = sm.a.a2; float* wf = sm.a.wf; float* hf = sm.a.hf;
            float* es = sm.a.es; float* alpha = sm.a.alpha;
            if (tid < 128) {
                v4i u = *(const v4i*)&hnewb[b * 1024 + tid * 8];
                *(v4i*)&zb[b * 2816 + 1792 + tid * 8] = u;   // z h-columns
#pragma unroll
                for (int q = 0; q < 4; ++q) {
                    unsigned int x = ((unsigned int*)&u)[q];
                    hf[tid * 8 + 2 * q]     = lo16(x);
                    hf[tid * 8 + 2 * q + 1] = hi16(x);
                }
            }
            wf[tid]       = Wfatt[tid];
            wf[tid + 256] = Wfatt[tid + 256];
            if (tid < 64)                                     // z emb-columns
                *(v4i*)&zb[b * 2816 + tid * 8] = *(const v4i*)&embb[(b * 24 + t) * 512 + tid * 8];
            __syncthreads();
            // GEMV: thread computes att2 outputs n=tid and n=tid+256.
            // 4 independent FMA chains for ILP; h broadcast from LDS.
            {
                const unsigned short* w0 = &Wdattb[(size_t)tid * 1024];
                const unsigned short* w1 = &Wdattb[(size_t)(tid + 256) * 1024];
                float s0 = 0.f, s1 = 0.f, s2 = 0.f, s3 = 0.f;
                for (int k = 0; k < 1024; k += 8) {
                    v4i u0 = *(const v4i*)&w0[k];
                    v4i u1 = *(const v4i*)&w1[k];
#pragma unroll
                    for (int q = 0; q < 4; ++q) {
                        unsigned int x0 = ((unsigned int*)&u0)[q];
                        unsigned int x1 = ((unsigned int*)&u1)[q];
                        float ha = hf[k + 2 * q], hb2 = hf[k + 2 * q + 1];
                        s0 += lo16(x0) * ha; s1 += hi16(x0) * hb2;
                        s2 += lo16(x1) * ha; s3 += hi16(x1) * hb2;
                    }
                }
                a2[tid]       = s0 + s1 + bdatt[tid];
                a2[tid + 256] = s2 + s3 + bdatt[tid + 256];
            }
            __syncthreads();
            // scores: one att1 row per wave-iteration
            for (int p = w; p < 49; p += 4) {
                v4i u = *(const v4i*)&att1b[(b * 49 + p) * 512 + lane * 8];
                v4f c0 = *(const v4f*)&a2[lane * 8], c1 = *(const v4f*)&a2[lane * 8 + 4];
                v4f w0 = *(const v4f*)&wf[lane * 8], w1 = *(const v4f*)&wf[lane * 8 + 4];
                float s = 0.f;
#pragma unroll
                for (int q = 0; q < 4; ++q) {
                    unsigned int x = ((unsigned int*)&u)[q];
                    float vlo = lo16(x), vhi = hi16(x);
                    float clo = (q < 2) ? c0[q * 2] : c1[q * 2 - 4];
                    float chi = (q < 2) ? c0[q * 2 + 1] : c1[q * 2 - 3];
                    float wlo = (q < 2) ? w0[q * 2] : w1[q * 2 - 4];
                    float whi = (q < 2) ? w0[q * 2 + 1] : w1[q * 2 - 3];
                    s += fmaxf(vlo + clo, 0.f) * wlo;
                    s += fmaxf(vhi + chi, 0.f) * whi;
                }
#pragma unroll
                for (int off = 32; off > 0; off >>= 1) s += __shfl_xor(s, off);
                if (lane == 0) es[p] = s + bfatt[0];
            }
            __syncthreads();
            if (w == 0) {
                float v = (lane < 49) ? es[lane] : -1e30f;
                float m = v;
#pragma unroll
                for (int off = 32; off > 0; off >>= 1) m = fmaxf(m, __shfl_xor(m, off));
                float e = (lane < 49) ? __expf(v - m) : 0.f;
                float s = e;
#pragma unroll
                for (int off = 32; off > 0; off >>= 1) s += __shfl_xor(s, off);
                if (lane < 49) alpha[lane] = e / s;
            }
            __syncthreads();
            if (tid < 160) {                                  // z ctx-columns
                const int jb = tid * 8;
                float acc[8];
#pragma unroll
                for (int q = 0; q < 8; ++q) acc[q] = 0.f;
                for (int p = 0; p < 49; ++p) {
                    v4i u = *(const v4i*)&encb[(b * 49 + p) * 1280 + jb];
                    float al = alpha[p];
#pragma unroll
                    for (int q = 0; q < 4; ++q) {
                        unsigned int x = ((unsigned int*)&u)[q];
                        acc[2 * q]     += al * lo16(x);
                        acc[2 * q + 1] += al * hi16(x);
                    }
                }
                *(v4i*)&zb[b * 2816 + 512 + jb] = pack8(acc);
            }
        }
        btarget += 256; gbar(barcnt, btarget);

        // ============ phaseB: gates GEMM + LSTM epilogue (all 256 blocks)
        {
            const int hb = bid * 4;
            const int rT = tid >> 5, cT = (tid & 31) * 8;
            const int gate = rT & 3, hco = rT >> 2;
            const int growB  = (gate * 1024 + hb + hco) * 2816;
            const int growB2 = (((rT + 8) & 3) * 1024 + hb + ((rT + 8) >> 2)) * 2816;
            v4f acc = {0.f, 0.f, 0.f, 0.f};
            v4i ra[8], rb[2];
#pragma unroll
            for (int i = 0; i < 8; ++i)
                ra[i] = *(const v4i*)&zb[(rT + i * 8) * 2816 + cT];
            rb[0] = *(const v4i*)&Wzb[growB + cT];
            rb[1] = *(const v4i*)&Wzb[growB2 + cT];
            for (int kt = 0; kt < 2816; kt += 256) {
#pragma unroll
                for (int i = 0; i < 8; ++i) *(v4i*)&sm.g.lA[(rT + i * 8) * 264 + cT] = ra[i];
                *(v4i*)&sm.g.lB[rT * 264 + cT] = rb[0];
                *(v4i*)&sm.g.lB[(rT + 8) * 264 + cT] = rb[1];
                __syncthreads();
                if (kt + 256 < 2816) {
#pragma unroll
                    for (int i = 0; i < 8; ++i)
                        ra[i] = *(const v4i*)&zb[(rT + i * 8) * 2816 + kt + 256 + cT];
                    rb[0] = *(const v4i*)&Wzb[growB + kt + 256 + cT];
                    rb[1] = *(const v4i*)&Wzb[growB2 + kt + 256 + cT];
                }
#pragma unroll
                for (int ks = 0; ks < 8; ++ks) {
                    v8s a = *(const v8s*)&sm.g.lA[(w * 16 + (lane & 15)) * 264 + ks * 32 + (lane >> 4) * 8];
                    v8s b = *(const v8s*)&sm.g.lB[(lane & 15) * 264 + ks * 32 + (lane >> 4) * 8];
                    acc = __builtin_amdgcn_mfma_f32_16x16x32_bf16(a, b, acc, 0, 0, 0);
                }
                __syncthreads();
            }
#pragma unroll
            for (int r = 0; r < 4; ++r) {
                int m = w * 16 + (lane >> 4) * 4 + r;   // = b
                int n = lane & 15;                      // = hco*4 + gate
                sm.g.gbuf[m * 20 + n] = acc[r];
            }
            __syncthreads();
            const int b = tid >> 2, hc2 = tid & 3, hidx = hb + hc2;
            float gi = sm.g.gbuf[b * 20 + hc2 * 4 + 0] + bz[hidx];
            float gf = sm.g.gbuf[b * 20 + hc2 * 4 + 1] + bz[1024 + hidx];
            float gg = sm.g.gbuf[b * 20 + hc2 * 4 + 2] + bz[2048 + hidx];
            float go = sm.g.gbuf[b * 20 + hc2 * 4 + 3] + bz[3072 + hidx];
            float cn = sigm(gf) * cst[b * 1024 + hidx] + sigm(gi) * tanhf(gg);
            float hn = sigm(go) * tanhf(cn);
            cst[b * 1024 + hidx] = cn;
            unsigned short h16 = f2bf(hn);
            hnewb[b * 1024 + hidx] = h16;
            Hallb[(size_t)t * 65536 + b * 1024 + hidx] = h16;
        }
        if (t < 23) { btarget += 256; gbar(barcnt, btarget); }
        // final step: kernel completion orders Hallb/cst before preds_k
    }
}

// ---------------------------------------------------------------------------
// preds: out = Hall[1536,1024] @ W_out[10000,1024]^T + b_out
// Tile 128x128, BK=64, reg-dbuf. grid = 960 with XCD-aware mapping so all 12
// m-blocks of one Wout n-strip land on the same XCD (strip fetched once).
// ---------------------------------------------------------------------------
__global__ __launch_bounds__(256) void preds_k(
    const unsigned short* __restrict__ Hall, const unsigned short* __restrict__ Wout,
    const float* __restrict__ bout, float* __restrict__ out)
{
    const int bidl = blockIdx.x;
    const int xcd = bidl & 7, loc = bidl >> 3;
    const int nbi = xcd * 10 + loc / 12;
    const int mbi = loc - (loc / 12) * 12;
    if (nbi >= 79) return;
    __shared__ unsigned short lA[128 * 72];
    __shared__ unsigned short lB[128 * 72];
    const int tid = threadIdx.x, lane = tid & 63, w = tid >> 6;
    const int mb = mbi * 128, nb = nbi * 128;
    const int rT = tid >> 3, cT = (tid & 7) * 8;
    v4f acc[2][8];
#pragma unroll
    for (int i = 0; i < 2; ++i)
#pragma unroll
        for (int f = 0; f < 8; ++f) acc[i][f] = (v4f){0.f, 0.f, 0.f, 0.f};
    v4i ra[4], rb[4];
#pragma unroll
    for (int i = 0; i < 4; ++i) {
        ra[i] = *(const v4i*)&Hall[(mb + rT + i * 32) * 1024 + cT];
        int n2 = nb + rT + i * 32; if (n2 > 9999) n2 = 9999;
        rb[i] = *(const v4i*)&Wout[n2 * 1024 + cT];
    }
    for (int kt = 0; kt < 1024; kt += 64) {
#pragma unroll
        for (int i = 0; i < 4; ++i) {
            *(v4i*)&lA[(rT + i * 32) * 72 + cT] = ra[i];
            *(v4i*)&lB[(rT + i * 32) * 72 + cT] = rb[i];
        }
        __syncthreads();
        if (kt + 64 < 1024) {
#pragma unroll
            for (int i = 0; i < 4; ++i) {
                ra[i] = *(const v4i*)&Hall[(mb + rT + i * 32) * 1024 + kt + 64 + cT];
                int n2 = nb + rT + i * 32; if (n2 > 9999) n2 = 9999;
                rb[i] = *(const v4i*)&Wout[n2 * 1024 + kt + 64 + cT];
            }
        }
#pragma unroll
        for (int ks = 0; ks < 2; ++ks) {
            int ko = ks * 32 + (lane >> 4) * 8;
            v8s a0 = *(const v8s*)&lA[(w * 32 + (lane & 15)) * 72 + ko];
            v8s a1 = *(const v8s*)&lA[(w * 32 + 16 + (lane & 15)) * 72 + ko];
#pragma unroll
            for (int f = 0; f < 8; ++f) {
                v8s b = *(const v8s*)&lB[(f * 16 + (lane & 15)) * 72 + ko];
                acc[0][f] = __builtin_amdgcn_mfma_f32_16x16x32_bf16(a0, b, acc[0][f], 0, 0, 0);
                acc[1][f] = __builtin_amdgcn_mfma_f32_16x16x32_bf16(a1, b, acc[1][f], 0, 0, 0);
            }
        }
        __syncthreads();
    }
#pragma unroll
    for (int f = 0; f < 8; ++f) {
        int n = nb + f * 16 + (lane & 15);
        if (n < 10000) {
            float bs = bout[n];
#pragma unroll
            for (int i = 0; i < 2; ++i)
#pragma unroll
                for (int r = 0; r < 4; ++r) {
                    int m = mb + w * 32 + i * 16 + (lane >> 4) * 4 + r;
                    int tt = m >> 6, bb = m & 63;
                    out[(bb * 24 + tt) * 10000 + n] = acc[i][f][r] + bs;
                }
        }
    }
}

// ---------------------------------------------------------------------------
extern "C" void kernel_launch(void* const* d_in, const int* in_sizes, int n_in,
                              void* d_out, int out_size, void* d_ws, size_t ws_size,
                              hipStream_t stream)
{
    const float* enc   = (const float*)d_in[0];
    const int*   caps  = (const int*)d_in[1];
    const float* embed = (const float*)d_in[2];
    const float* Weatt = (const float*)d_in[3];
    const float* beatt = (const float*)d_in[4];
    const float* Wdatt = (const float*)d_in[5];
    const float* bdatt = (const float*)d_in[6];
    const float* Wfatt = (const float*)d_in[7];
    const float* bfatt = (const float*)d_in[8];
    const float* Wih   = (const float*)d_in[9];
    const float* bih   = (const float*)d_in[10];
    const float* Whh   = (const float*)d_in[11];
    const float* bhh   = (const float*)d_in[12];
    const float* Wh0   = (const float*)d_in[13];
    const float* bh0   = (const float*)d_in[14];
    const float* Wc0   = (const float*)d_in[15];
    const float* bc0   = (const float*)d_in[16];
    const float* WoutF = (const float*)d_in[17];
    const float* bout  = (const float*)d_in[18];
    float* out = (float*)d_out;

    char* ws = (char*)d_ws;
    size_t off = 0;
    auto carve = [&](size_t bytes) -> void* {
        void* p = ws + off; off += (bytes + 255) & ~(size_t)255; return p;
    };
    unsigned short* Wzb    = (unsigned short*)carve(11534336ull * 2);
    unsigned short* Woutb  = (unsigned short*)carve(10240000ull * 2);
    unsigned short* Weattb = (unsigned short*)carve(655360ull * 2);
    unsigned short* Wdattb = (unsigned short*)carve(524288ull * 2);
    unsigned short* Wh0b   = (unsigned short*)carve(1310720ull * 2);
    unsigned short* Wc0b   = (unsigned short*)carve(1310720ull * 2);
    unsigned short* encb   = (unsigned short*)carve(4014080ull * 2);
    unsigned short* embb   = (unsigned short*)carve(786432ull * 2);
    unsigned short* meanb  = (unsigned short*)carve(81920ull * 2);
    unsigned short* att1b  = (unsigned short*)carve(1605632ull * 2);
    unsigned short* Hallb  = (unsigned short*)carve(1572864ull * 2);
    unsigned short* zb     = (unsigned short*)carve(180224ull * 2);
    unsigned short* hnewb  = (unsigned short*)carve(65536ull * 2);
    float* bz   = (float*)carve(4096ull * 4);
    float* cst  = (float*)carve(65536ull * 4);
    int*   barcnt = (int*)carve(256);

    // barrier counter must be 0 at loop_k entry every iteration
    hipMemsetAsync(barcnt, 0, 256, stream);

    uber_init<<<14874, 256, 0, stream>>>(Wih, Whh, bih, bhh, WoutF, Weatt, Wdatt,
        Wh0, Wc0, enc, caps, embed, Wzb, Woutb, Weattb, Wdattb, Wh0b, Wc0b,
        encb, embb, meanb, bz);

    // h0 -> hnewb (bf16, ldc=1024); c0 -> cst (f32)
    gemm64_bn16<1><<<64, 256, 0, stream>>>(meanb, 1280, Wh0b, 1280, bh0, hnewb, 1024);
    gemm64_bn16<0><<<64, 256, 0, stream>>>(meanb, 1280, Wc0b, 1280, bc0, cst, 1024);

    gemm_att1_k<<<dim3(8, 49), 256, 0, stream>>>(encb, Weattb, beatt, att1b);

    // whole 24-step decoder loop, one persistent kernel + software barriers
    loop_k<<<256, 256, 0, stream>>>(zb, Wdattb, bdatt, att1b, Wfatt,
        bfatt, encb, embb, Wzb, bz, cst, Hallb, hnewb, barcnt);

    preds_k<<<960, 256, 0, stream>>>(Hallb, Woutb, bout, out);
}